// Round 6
// baseline (502.439 us; speedup 1.0000x reference)
//
#include <hip/hip_runtime.h>

typedef __attribute__((ext_vector_type(4))) float f32x4;
typedef __attribute__((ext_vector_type(8))) short short8;
typedef __attribute__((ext_vector_type(4))) short short4v;

#define MFMA_B16(a,b,c) __builtin_amdgcn_mfma_f32_16x16x32_bf16((a),(b),(c),0,0,0)

static __device__ __forceinline__ unsigned short f2bf(float x){
  unsigned int u = __float_as_uint(x);
  u += 0x7fffu + ((u >> 16) & 1u);
  return (unsigned short)(u >> 16);
}

static __device__ __forceinline__ short8 pack8(f32x4 a, f32x4 b){
  short8 r;
  r[0]=(short)f2bf(a[0]); r[1]=(short)f2bf(a[1]); r[2]=(short)f2bf(a[2]); r[3]=(short)f2bf(a[3]);
  r[4]=(short)f2bf(b[0]); r[5]=(short)f2bf(b[1]); r[6]=(short)f2bf(b[2]); r[7]=(short)f2bf(b[3]);
  return r;
}

// C-layout 16x16 tile X[row=4q+r][col=c] -> A/B-frag of X^T orientation:
// frag[j] = X[row=q*8+j][col=c]; src lane = 16*(2q + (j>>2)) + c, src reg j&3.
// Valid for target quads 0,1 (k<16); caller zeroes quads 2,3.
static __device__ __forceinline__ short8 xpose(const f32x4& X, int lane){
  const int c = lane & 15, q = lane >> 4;
  const int s0 = (q*32 + c) & 63, s1 = (q*32 + 16 + c) & 63;
  f32x4 lo, hi;
  #pragma unroll
  for (int r = 0; r < 4; ++r){ lo[r] = __shfl(X[r], s0); hi[r] = __shfl(X[r], s1); }
  return pack8(lo, hi);
}

__global__ void prep_w(const float* __restrict__ ipw, const float* __restrict__ opw,
                       unsigned short* __restrict__ wbf){
  int i = blockIdx.x * 256 + threadIdx.x;
  float v = (i < 384*128) ? ipw[i] : opw[i - 384*128];
  wbf[i] = f2bf(v);
}

#define STR 136   // shorts per staged row (128 + 8 pad)

// ============================ group2 kernel ============================
// (unchanged from R5: 256 threads, 2 heads/wave, TTP=7, S^T softmax)
template<int TTP>
__global__ __launch_bounds__(256, 2)
void fused_attn(const float* __restrict__ feat,
                const float* __restrict__ pos,
                const int* __restrict__ inds,
                int LW,
                const unsigned short* __restrict__ wqkv,   // bf16 [384][128]
                const unsigned short* __restrict__ wout,   // bf16 [128][128]
                const float* __restrict__ ipb, const float* __restrict__ opb,
                float* __restrict__ out)
{
  constexpr int PSTR = 16*(TTP+1) + 8;   // P-strip row length (keys + tail + pad)
  extern __shared__ __align__(16) unsigned short smem[];
  unsigned short* sQK = smem;                     // [16*TTP][STR] bf16 (f+pos)
  unsigned short* sF  = smem + 16*TTP*STR;        // [16*TTP][STR] bf16 f, reused for O
  unsigned short* sPb = smem + 2*16*TTP*STR;      // per-wave [16][PSTR] P strips

  const int w = blockIdx.x;
  const int Lv = (w & 1) ? (LW >> 1) : LW;
  const int T  = (Lv + 15) >> 4;              // query/key tiles (<= TTP)
  const long ibase = (long)w * LW;
  const int tid = threadIdx.x;
  const int wv = tid >> 6, lane = tid & 63, c = lane & 15, q = lane >> 4;
  const short8 Z8 = {0,0,0,0,0,0,0,0};
  const f32x4  Z4 = {0.f,0.f,0.f,0.f};

  {
    const int rg = tid >> 4, ch = tid & 15;
    #pragma unroll
    for (int s = 0; s < TTP; ++s){
      if (s < T){
        const int row = s*16 + rg;
        short8 fv = Z8, qv = Z8;
        if (row < Lv){
          const int tok = inds[ibase + row];
          const float* fr = feat + (long)tok*128 + ch*8;
          const float* pr = pos + (ibase + row)*128 + ch*8;
          f32x4 f0 = *(const f32x4*)fr, f1 = *(const f32x4*)(fr+4);
          f32x4 p0 = *(const f32x4*)pr, p1 = *(const f32x4*)(pr+4);
          fv = pack8(f0, f1); qv = pack8(f0+p0, f1+p1);
        }
        *(short8*)&sF [row*STR + ch*8] = fv;
        *(short8*)&sQK[row*STR + ch*8] = qv;
      }
    }
  }
  __syncthreads();

  unsigned short* Pb = sPb + wv*16*PSTR;
  if (T & 1){
    const short4v z4 = {0,0,0,0};
    *(short4v*)&Pb[c*PSTR + 16*T + 4*q] = z4;
  }
  short4v of[2][TTP];

  #pragma unroll
  for (int hh = 0; hh < 2; ++hh){
    const int h = wv*2 + hh;
    short8 bQ[4], bK[4], bV[4];
    const unsigned short* wr = wqkv + (h*16 + c)*128 + q*8;
    #pragma unroll
    for (int kk = 0; kk < 4; ++kk){
      bQ[kk] = *(const short8*)(wr + kk*32);
      bK[kk] = *(const short8*)(wr + kk*32 + 128*128);
      bV[kk] = *(const short8*)(wr + kk*32 + 2*128*128);
    }
    float bq_r[4], bk_r[4];
    #pragma unroll
    for (int r = 0; r < 4; ++r){
      bq_r[r] = ipb[h*16 + 4*q + r];
      bk_r[r] = ipb[128 + h*16 + 4*q + r];
    }
    const float bv_c = ipb[256 + h*16 + c];

    short8 qAf[TTP], kBf[TTP];
    f32x4 va[TTP];
    #pragma unroll
    for (int t = 0; t < TTP; ++t) va[t] = Z4;

    #pragma unroll
    for (int t = 0; t < TTP; ++t) if (t < T){
      f32x4 qt = Z4, kt = Z4, vt = Z4;
      #pragma unroll
      for (int kk = 0; kk < 4; ++kk){
        const short8 aQ = *(const short8*)&sQK[(16*t + c)*STR + kk*32 + q*8];
        const short8 aF = *(const short8*)&sF [(16*t + c)*STR + kk*32 + q*8];
        qt = MFMA_B16(bQ[kk], aQ, qt);
        kt = MFMA_B16(bK[kk], aQ, kt);
        vt = MFMA_B16(aF, bV[kk], vt);
      }
      #pragma unroll
      for (int r = 0; r < 4; ++r){
        qt[r] = (qt[r] + bq_r[r]) * 0.25f;
        kt[r] += bk_r[r];
        const int key = 16*t + 4*q + r;
        vt[r] = (key < Lv) ? (vt[r] + bv_c) : 0.f;
      }
      short8 tq8 = xpose(qt, lane);
      qAf[t] = (q < 2) ? tq8 : Z8;
      short8 tk8 = xpose(kt, lane);
      kBf[t] = (q < 2) ? tk8 : Z8;
      va[t] = vt;
    }

    short8 vBf[(TTP+1)/2];
    #pragma unroll
    for (int u = 0; u < (TTP+1)/2; ++u) if (u < ((T+1)>>1)){
      const int s0 = 32*(q & 1) + c, s1 = s0 + 16;
      f32x4 A0 = va[2*u];
      f32x4 A1 = (2*u+1 < TTP) ? va[2*u+1] : Z4;
      f32x4 lo, hi;
      #pragma unroll
      for (int r = 0; r < 4; ++r){
        float a0 = __shfl(A0[r], s0), a1 = __shfl(A1[r], s0);
        lo[r] = (q < 2) ? a0 : a1;
        float b0 = __shfl(A0[r], s1), b1 = __shfl(A1[r], s1);
        hi[r] = (q < 2) ? b0 : b1;
      }
      vBf[u] = pack8(lo, hi);
    }

    #pragma unroll
    for (int t = 0; t < TTP; ++t) if (t < T){
      f32x4 St[TTP];
      #pragma unroll
      for (int tk = 0; tk < TTP; ++tk) if (tk < T){
        St[tk] = MFMA_B16(kBf[tk], qAf[t], Z4);     // C [key][query] = S^T
        #pragma unroll
        for (int r = 0; r < 4; ++r){
          const int key = 16*tk + 4*q + r;
          if (key >= Lv) St[tk][r] = -1e30f;
        }
      }
      f32x4 mm = {-1e30f,-1e30f,-1e30f,-1e30f};
      #pragma unroll
      for (int tk = 0; tk < TTP; ++tk) if (tk < T){
        mm[0]=fmaxf(mm[0],St[tk][0]); mm[1]=fmaxf(mm[1],St[tk][1]);
        mm[2]=fmaxf(mm[2],St[tk][2]); mm[3]=fmaxf(mm[3],St[tk][3]);
      }
      float m = fmaxf(fmaxf(mm[0],mm[1]), fmaxf(mm[2],mm[3]));
      m = fmaxf(m, __shfl_xor(m, 16));
      m = fmaxf(m, __shfl_xor(m, 32));
      f32x4 ss = Z4;
      #pragma unroll
      for (int tk = 0; tk < TTP; ++tk) if (tk < T){
        #pragma unroll
        for (int r = 0; r < 4; ++r){
          float e = __expf(St[tk][r] - m);
          St[tk][r] = e; ss[r] += e;
        }
      }
      float sum = (ss[0]+ss[1]) + (ss[2]+ss[3]);
      sum += __shfl_xor(sum, 16);
      sum += __shfl_xor(sum, 32);
      const float inv = 1.0f / sum;
      #pragma unroll
      for (int tk = 0; tk < TTP; ++tk) if (tk < T){
        short4v p4;
        #pragma unroll
        for (int r = 0; r < 4; ++r) p4[r] = (short)f2bf(St[tk][r] * inv);
        *(short4v*)&Pb[c*PSTR + 16*tk + 4*q] = p4;
      }
      f32x4 o = Z4;
      #pragma unroll
      for (int u = 0; u < (TTP+1)/2; ++u) if (u < ((T+1)>>1)){
        const short8 ap = *(const short8*)&Pb[c*PSTR + 32*u + q*8];
        o = MFMA_B16(ap, vBf[u], o);
      }
      short4v ob;
      #pragma unroll
      for (int r = 0; r < 4; ++r) ob[r] = (short)f2bf(o[r]);
      of[hh][t] = ob;
    }
  } // hh

  __syncthreads();
  #pragma unroll
  for (int hh = 0; hh < 2; ++hh){
    const int h = wv*2 + hh;
    #pragma unroll
    for (int t = 0; t < TTP; ++t) if (t < T){
      #pragma unroll
      for (int r = 0; r < 4; ++r)
        sF[(16*t + 4*q + r)*STR + h*16 + c] = (unsigned short)of[hh][t][r];
    }
  }
  __syncthreads();

  float bo_r[8];
  #pragma unroll
  for (int ct = 0; ct < 8; ++ct) bo_r[ct] = opb[ct*16 + c];
  #pragma unroll
  for (int ti = 0; ti < 2; ++ti){
    const int t = wv + ti*4;
    if (t < T){
      f32x4 acc[8];
      #pragma unroll
      for (int ct = 0; ct < 8; ++ct) acc[ct] = Z4;
      #pragma unroll
      for (int p = 0; p < 4; ++p){
        const short8 ao = *(const short8*)&sF[(16*t + c)*STR + p*32 + q*8];
        #pragma unroll
        for (int ct = 0; ct < 8; ++ct){
          const short8 bw = *(const short8*)&wout[(ct*16 + c)*128 + p*32 + q*8];
          acc[ct] = MFMA_B16(ao, bw, acc[ct]);
        }
      }
      #pragma unroll
      for (int r = 0; r < 4; ++r){
        const int l = 16*t + 4*q + r;
        if (l < Lv){
          const int tok = inds[ibase + l];
          float* orow = out + (long)tok*128;
          #pragma unroll
          for (int ct = 0; ct < 8; ++ct)
            orow[ct*16 + c] = acc[ct][r] + bo_r[ct];
        }
      }
    }
  }
}

// ============================ group1 kernel ============================
// 512 threads = 8 waves, ONE head per wave (h = wv), TT3 = 3 tiles max.
// Per-wave live state ~100 VGPR -> fits the 128-VGPR budget of 4 waves/SIMD,
// so __launch_bounds__(512,4) enables 2 blocks/CU = 16 waves/CU.
// P strips overlap the sQK/sF region (dead after projection, barrier-guarded).
#define TT3 3
#define PSTR3 (16*(TT3+1) + 8)   // 72

__global__ __launch_bounds__(512, 4)
void fused_attn3_w8(const float* __restrict__ feat,
                    const float* __restrict__ pos,
                    const int* __restrict__ inds,
                    const unsigned short* __restrict__ wqkv,
                    const unsigned short* __restrict__ wout,
                    const float* __restrict__ ipb, const float* __restrict__ opb,
                    float* __restrict__ out)
{
  extern __shared__ __align__(16) unsigned short smem[];
  unsigned short* sQK = smem;                 // [48][STR]; P strips overlap later
  unsigned short* sF  = smem + 48*STR;        // [48][STR]; O buffer later

  const int w = blockIdx.x;
  const int LW = 36;
  const int Lv = (w & 1) ? 18 : 36;
  const int T  = (Lv + 15) >> 4;              // 3 (even w) or 2 (odd w)
  const long ibase = (long)w * LW;
  const int tid = threadIdx.x;
  const int wv = tid >> 6, lane = tid & 63, c = lane & 15, q = lane >> 4;
  const short8 Z8 = {0,0,0,0,0,0,0,0};
  const f32x4  Z4 = {0.f,0.f,0.f,0.f};

  // ---- stage f and qk=f+pos; 32 rows x 16 chunks per sweep (2 sweeps)
  {
    const int rg = tid >> 4, ch = tid & 15;   // rg 0..31
    #pragma unroll
    for (int s = 0; s < 2; ++s){
      const int row = s*32 + rg;
      if (row < 16*T){
        short8 fv = Z8, qv = Z8;
        if (row < Lv){
          const int tok = inds[ibase + row];
          const float* fr = feat + (long)tok*128 + ch*8;
          const float* pr = pos + (ibase + row)*128 + ch*8;
          f32x4 f0 = *(const f32x4*)fr, f1 = *(const f32x4*)(fr+4);
          f32x4 p0 = *(const f32x4*)pr, p1 = *(const f32x4*)(pr+4);
          fv = pack8(f0, f1); qv = pack8(f0+p0, f1+p1);
        }
        *(short8*)&sF [row*STR + ch*8] = fv;
        *(short8*)&sQK[row*STR + ch*8] = qv;
      }
    }
  }
  __syncthreads();

  const int h = wv;                           // one head per wave
  short8 bQ[4], bK[4], bV[4];
  const unsigned short* wr = wqkv + (h*16 + c)*128 + q*8;
  #pragma unroll
  for (int kk = 0; kk < 4; ++kk){
    bQ[kk] = *(const short8*)(wr + kk*32);
    bK[kk] = *(const short8*)(wr + kk*32 + 128*128);
    bV[kk] = *(const short8*)(wr + kk*32 + 2*128*128);
  }
  float bq_r[4], bk_r[4];
  #pragma unroll
  for (int r = 0; r < 4; ++r){
    bq_r[r] = ipb[h*16 + 4*q + r];
    bk_r[r] = ipb[128 + h*16 + 4*q + r];
  }
  const float bv_c = ipb[256 + h*16 + c];

  short8 qAf[TT3], kBf[TT3];
  f32x4 va[TT3];
  #pragma unroll
  for (int t = 0; t < TT3; ++t) va[t] = Z4;

  #pragma unroll
  for (int t = 0; t < TT3; ++t) if (t < T){
    f32x4 qt = Z4, kt = Z4, vt = Z4;
    #pragma unroll
    for (int kk = 0; kk < 4; ++kk){
      const short8 aQ = *(const short8*)&sQK[(16*t + c)*STR + kk*32 + q*8];
      const short8 aF = *(const short8*)&sF [(16*t + c)*STR + kk*32 + q*8];
      qt = MFMA_B16(bQ[kk], aQ, qt);
      kt = MFMA_B16(bK[kk], aQ, kt);
      vt = MFMA_B16(aF, bV[kk], vt);
    }
    #pragma unroll
    for (int r = 0; r < 4; ++r){
      qt[r] = (qt[r] + bq_r[r]) * 0.25f;
      kt[r] += bk_r[r];
      const int key = 16*t + 4*q + r;
      vt[r] = (key < Lv) ? (vt[r] + bv_c) : 0.f;
    }
    short8 tq8 = xpose(qt, lane);
    qAf[t] = (q < 2) ? tq8 : Z8;
    short8 tk8 = xpose(kt, lane);
    kBf[t] = (q < 2) ? tk8 : Z8;
    va[t] = vt;
  }

  short8 vBf[2];
  #pragma unroll
  for (int u = 0; u < 2; ++u) if (u < ((T+1)>>1)){
    const int s0 = 32*(q & 1) + c, s1 = s0 + 16;
    f32x4 A0 = va[2*u];
    f32x4 A1 = (2*u+1 < TT3) ? va[2*u+1] : Z4;
    f32x4 lo, hi;
    #pragma unroll
    for (int r = 0; r < 4; ++r){
      float a0 = __shfl(A0[r], s0), a1 = __shfl(A1[r], s0);
      lo[r] = (q < 2) ? a0 : a1;
      float b0 = __shfl(A0[r], s1), b1 = __shfl(A1[r], s1);
      hi[r] = (q < 2) ? b0 : b1;
    }
    vBf[u] = pack8(lo, hi);
  }

  // projection reads of sQK/sF done -> P strips may overwrite that region
  __syncthreads();

  unsigned short* Pb = smem + wv*16*PSTR3;    // per-wave [16][PSTR3] strip
  if (T & 1){
    const short4v z4 = {0,0,0,0};
    *(short4v*)&Pb[c*PSTR3 + 16*T + 4*q] = z4;
  }
  short4v of[TT3];

  #pragma unroll
  for (int t = 0; t < TT3; ++t) if (t < T){
    f32x4 St[TT3];
    #pragma unroll
    for (int tk = 0; tk < TT3; ++tk) if (tk < T){
      St[tk] = MFMA_B16(kBf[tk], qAf[t], Z4);       // C [key][query] = S^T
      #pragma unroll
      for (int r = 0; r < 4; ++r){
        const int key = 16*tk + 4*q + r;
        if (key >= Lv) St[tk][r] = -1e30f;
      }
    }
    f32x4 mm = {-1e30f,-1e30f,-1e30f,-1e30f};
    #pragma unroll
    for (int tk = 0; tk < TT3; ++tk) if (tk < T){
      mm[0]=fmaxf(mm[0],St[tk][0]); mm[1]=fmaxf(mm[1],St[tk][1]);
      mm[2]=fmaxf(mm[2],St[tk][2]); mm[3]=fmaxf(mm[3],St[tk][3]);
    }
    float m = fmaxf(fmaxf(mm[0],mm[1]), fmaxf(mm[2],mm[3]));
    m = fmaxf(m, __shfl_xor(m, 16));
    m = fmaxf(m, __shfl_xor(m, 32));
    f32x4 ss = Z4;
    #pragma unroll
    for (int tk = 0; tk < TT3; ++tk) if (tk < T){
      #pragma unroll
      for (int r = 0; r < 4; ++r){
        float e = __expf(St[tk][r] - m);
        St[tk][r] = e; ss[r] += e;
      }
    }
    float sum = (ss[0]+ss[1]) + (ss[2]+ss[3]);
    sum += __shfl_xor(sum, 16);
    sum += __shfl_xor(sum, 32);
    const float inv = 1.0f / sum;
    #pragma unroll
    for (int tk = 0; tk < TT3; ++tk) if (tk < T){
      short4v p4;
      #pragma unroll
      for (int r = 0; r < 4; ++r) p4[r] = (short)f2bf(St[tk][r] * inv);
      *(short4v*)&Pb[c*PSTR3 + 16*tk + 4*q] = p4;
    }
    f32x4 o = Z4;
    #pragma unroll
    for (int u = 0; u < 2; ++u) if (u < ((T+1)>>1)){
      const short8 ap = *(const short8*)&Pb[c*PSTR3 + 32*u + q*8];
      o = MFMA_B16(ap, vBf[u], o);
    }
    short4v ob;
    #pragma unroll
    for (int r = 0; r < 4; ++r) ob[r] = (short)f2bf(o[r]);
    of[t] = ob;
  }

  __syncthreads();   // all P strips dead; sF region free for O
  #pragma unroll
  for (int t = 0; t < TT3; ++t) if (t < T){
    #pragma unroll
    for (int r = 0; r < 4; ++r)
      sF[(16*t + 4*q + r)*STR + h*16 + c] = (unsigned short)of[t][r];
  }
  __syncthreads();   // O complete

  // ---- out projection: wave -> (tile wv>>1, ct half wv&1)
  {
    const int t = wv >> 1;
    const int cth = (wv & 1) * 4;
    if (t < T){
      float bo_r[4];
      #pragma unroll
      for (int cc = 0; cc < 4; ++cc) bo_r[cc] = opb[(cth + cc)*16 + c];
      f32x4 acc[4];
      #pragma unroll
      for (int cc = 0; cc < 4; ++cc) acc[cc] = Z4;
      #pragma unroll
      for (int p = 0; p < 4; ++p){
        const short8 ao = *(const short8*)&sF[(16*t + c)*STR + p*32 + q*8];
        #pragma unroll
        for (int cc = 0; cc < 4; ++cc){
          const short8 bw = *(const short8*)&wout[((cth + cc)*16 + c)*128 + p*32 + q*8];
          acc[cc] = MFMA_B16(ao, bw, acc[cc]);
        }
      }
      #pragma unroll
      for (int r = 0; r < 4; ++r){
        const int l = 16*t + 4*q + r;
        if (l < Lv){
          const int tok = inds[ibase + l];
          float* orow = out + (long)tok*128;
          #pragma unroll
          for (int cc = 0; cc < 4; ++cc)
            orow[(cth + cc)*16 + c] = acc[cc][r] + bo_r[cc];
        }
      }
    }
  }
}

extern "C" void kernel_launch(void* const* d_in, const int* in_sizes, int n_in,
                              void* d_out, int out_size, void* d_ws, size_t ws_size,
                              hipStream_t stream) {
  const float* feat = (const float*)d_in[0];
  const float* pos1 = (const float*)d_in[1];
  const float* pos2 = (const float*)d_in[2];
  const float* ipw  = (const float*)d_in[3];
  const float* ipb  = (const float*)d_in[4];
  const float* opw  = (const float*)d_in[5];
  const float* opb  = (const float*)d_in[6];
  const int*   inds1 = (const int*)d_in[7];
  const int*   inds2 = (const int*)d_in[8];
  float* out = (float*)d_out;
  unsigned short* wbf = (unsigned short*)d_ws;   // 384*128 + 128*128 bf16
  unsigned short* wob = wbf + 384*128;

  prep_w<<<dim3(256), dim3(256), 0, stream>>>(ipw, opw, wbf);

  // group2 (L=100): TTP=7, 256 threads. LDS = 78336 B -> 2 blocks/CU
  {
    const int lds2 = (2*112*STR + 4*16*(16*8 + 8)) * 2;
    hipFuncSetAttribute((const void*)fused_attn<7>,
                        hipFuncAttributeMaxDynamicSharedMemorySize, lds2);
    fused_attn<7><<<dim3(1024), dim3(256), lds2, stream>>>(
        feat, pos2, inds2, 100, wbf, wob, ipb, opb, out);
  }
  // group1 (L=36): 512 threads, 1 head/wave. LDS = 2*48*136*2 = 26112 B;
  // P strips (8*16*72*2 = 18432 B) overlap sQK/sF, barrier-guarded.
  {
    const int lds1 = 2*48*STR*2;
    hipFuncSetAttribute((const void*)fused_attn3_w8,
                        hipFuncAttributeMaxDynamicSharedMemorySize, lds1);
    fused_attn3_w8<<<dim3(4096), dim3(512), lds1, stream>>>(
        feat, pos1, inds1, wbf, wob, ipb, opb, out);
  }
}

// Round 7
// 475.135 us; speedup vs baseline: 1.0575x; 1.0575x over previous
//
#include <hip/hip_runtime.h>

typedef __attribute__((ext_vector_type(4))) float f32x4;
typedef __attribute__((ext_vector_type(8))) short short8;
typedef __attribute__((ext_vector_type(4))) short short4v;

#define MFMA_B16(a,b,c) __builtin_amdgcn_mfma_f32_16x16x32_bf16((a),(b),(c),0,0,0)

static __device__ __forceinline__ unsigned short f2bf(float x){
  unsigned int u = __float_as_uint(x);
  u += 0x7fffu + ((u >> 16) & 1u);
  return (unsigned short)(u >> 16);
}

static __device__ __forceinline__ short8 pack8(f32x4 a, f32x4 b){
  short8 r;
  r[0]=(short)f2bf(a[0]); r[1]=(short)f2bf(a[1]); r[2]=(short)f2bf(a[2]); r[3]=(short)f2bf(a[3]);
  r[4]=(short)f2bf(b[0]); r[5]=(short)f2bf(b[1]); r[6]=(short)f2bf(b[2]); r[7]=(short)f2bf(b[3]);
  return r;
}

static __device__ __forceinline__ short4v pack4(const f32x4& a){
  short4v r;
  r[0]=(short)f2bf(a[0]); r[1]=(short)f2bf(a[1]); r[2]=(short)f2bf(a[2]); r[3]=(short)f2bf(a[3]);
  return r;
}

__global__ void prep_w(const float* __restrict__ ipw, const float* __restrict__ opw,
                       unsigned short* __restrict__ wbf){
  int i = blockIdx.x * 256 + threadIdx.x;
  float v = (i < 384*128) ? ipw[i] : opw[i - 384*128];
  wbf[i] = f2bf(v);
}

#define STR 136   // shorts per staged row (128 + 8 pad)

// Head-per-wave fused window attention (2 heads/wave, 4 waves).
// Templated on max tile count TTP: group1 (L=36) -> TTP=3, group2 (L=100) -> TTP=7.
// Transposes (Q^T/K^T tile -> MFMA frag) done via per-wave LDS round-trip:
// lane(q,c) writes its 4 C-values X[4q+r][c] as one b64 at strip[c][4q]
// (materializing X^T), then reads the frag as one b128 at strip[c][q*8] —
// replaces 16 ds_bpermute + pack per transpose.  V tiles are written directly
// into the P-strip region (dead until P is written); vBf = one b128 read.
template<int TTP>
__global__ __launch_bounds__(256, 2)
void fused_attn(const float* __restrict__ feat,
                const float* __restrict__ pos,
                const int* __restrict__ inds,
                int LW,
                const unsigned short* __restrict__ wqkv,   // bf16 [384][128]
                const unsigned short* __restrict__ wout,   // bf16 [128][128]
                const float* __restrict__ ipb, const float* __restrict__ opb,
                float* __restrict__ out)
{
  constexpr int PSTR = 16*(TTP+1) + 8;   // P/vT strip row length
  constexpr int STRT = 24;               // transient transpose strip row length
  extern __shared__ __align__(16) unsigned short smem[];
  unsigned short* sQK = smem;                     // [16*TTP][STR] bf16 (f+pos)
  unsigned short* sF  = smem + 16*TTP*STR;        // [16*TTP][STR] bf16 f, reused for O
  unsigned short* sPb = smem + 2*16*TTP*STR;      // per-wave [16][PSTR] vT/P strips
  unsigned short* sTs = smem + 2*16*TTP*STR + 4*16*PSTR;  // per-wave [16][STRT]

  const int w = blockIdx.x;
  const int Lv = (w & 1) ? (LW >> 1) : LW;
  const int T  = (Lv + 15) >> 4;              // query/key tiles (<= TTP)
  const long ibase = (long)w * LW;
  const int tid = threadIdx.x;
  const int wv = tid >> 6, lane = tid & 63, c = lane & 15, q = lane >> 4;
  const short8 Z8 = {0,0,0,0,0,0,0,0};
  const f32x4  Z4 = {0.f,0.f,0.f,0.f};

  // ---- stage f and qk=f+pos as bf16 (zero invalid rows); 16 rows x 16 chunks per sweep
  {
    const int rg = tid >> 4, ch = tid & 15;
    #pragma unroll
    for (int s = 0; s < TTP; ++s){
      if (s < T){
        const int row = s*16 + rg;
        short8 fv = Z8, qv = Z8;
        if (row < Lv){
          const int tok = inds[ibase + row];
          const float* fr = feat + (long)tok*128 + ch*8;
          const float* pr = pos + (ibase + row)*128 + ch*8;
          f32x4 f0 = *(const f32x4*)fr, f1 = *(const f32x4*)(fr+4);
          f32x4 p0 = *(const f32x4*)pr, p1 = *(const f32x4*)(pr+4);
          fv = pack8(f0, f1); qv = pack8(f0+p0, f1+p1);
        }
        *(short8*)&sF [row*STR + ch*8] = fv;
        *(short8*)&sQK[row*STR + ch*8] = qv;
      }
    }
  }
  __syncthreads();

  unsigned short* Pb = sPb + wv*16*PSTR;
  unsigned short* Ts = sTs + wv*16*STRT;
  // Zero key block [16T, 16T+16) when T is odd: vBf's last 32-key group and
  // PV's A-frag read cover tile T, which is never written by vT or P.
  // Stays zero through both heads (nothing writes >= col 16T).
  if (T & 1){
    const short4v z4 = {0,0,0,0};
    *(short4v*)&Pb[c*PSTR + 16*T + 4*q] = z4;
  }
  short4v of[2][TTP];          // per-head O tiles, bf16-packed C-layout rows

  #pragma unroll
  for (int hh = 0; hh < 2; ++hh){
    const int h = wv*2 + hh;
    // W fragments: lane(q,c) holds W[h*16+c][q*8+j (+32kk)] — serves as
    // B-frag (x @ W^T) AND as A-frag (W @ x^T) simultaneously.
    short8 bQ[4], bK[4], bV[4];
    const unsigned short* wr = wqkv + (h*16 + c)*128 + q*8;
    #pragma unroll
    for (int kk = 0; kk < 4; ++kk){
      bQ[kk] = *(const short8*)(wr + kk*32);
      bK[kk] = *(const short8*)(wr + kk*32 + 128*128);
      bV[kk] = *(const short8*)(wr + kk*32 + 2*128*128);
    }
    float bq_r[4], bk_r[4];
    #pragma unroll
    for (int r = 0; r < 4; ++r){
      bq_r[r] = ipb[h*16 + 4*q + r];          // Q^T C-tile row = hd = 4q+r
      bk_r[r] = ipb[128 + h*16 + 4*q + r];
    }
    const float bv_c = ipb[256 + h*16 + c];   // V C-tile col = hd = c

    short8 qAf[TTP], kBf[TTP];

    #pragma unroll
    for (int t = 0; t < TTP; ++t) if (t < T){
      f32x4 qt = Z4, kt = Z4, vt = Z4;
      #pragma unroll
      for (int kk = 0; kk < 4; ++kk){
        const short8 aQ = *(const short8*)&sQK[(16*t + c)*STR + kk*32 + q*8];
        const short8 aF = *(const short8*)&sF [(16*t + c)*STR + kk*32 + q*8];
        qt = MFMA_B16(bQ[kk], aQ, qt);        // C [hd][query]  (Q^T)
        kt = MFMA_B16(bK[kk], aQ, kt);        // C [hd][key]    (K^T)
        vt = MFMA_B16(aF, bV[kk], vt);        // C [key][hd]
      }
      #pragma unroll
      for (int r = 0; r < 4; ++r){
        qt[r] = (qt[r] + bq_r[r]) * 0.25f;    // fold 1/sqrt(HD)
        kt[r] += bk_r[r];
        const int key = 16*t + 4*q + r;
        vt[r] = (key < Lv) ? (vt[r] + bv_c) : 0.f;  // zero padded keys (bias!)
      }
      // V tile -> vT strip (Pb region): lane writes V[16t+4q+r][c] to vT[c][16t+4q+r]
      *(short4v*)&Pb[c*PSTR + 16*t + 4*q] = pack4(vt);
      // Q^T frag via LDS round-trip (in-order same-wave LDS pipe)
      *(short4v*)&Ts[c*STRT + 4*q] = pack4(qt);
      const short8 qf = *(const short8*)&Ts[c*STRT + q*8];
      qAf[t] = (q < 2) ? qf : Z8;             // A[m=query][k=hd], k<16 padded
      // K^T frag (same strip, serialized; in-order pipe keeps read-before-write)
      *(short4v*)&Ts[c*STRT + 4*q] = pack4(kt);
      const short8 kf = *(const short8*)&Ts[c*STRT + q*8];
      kBf[t] = (q < 2) ? kf : Z8;             // B[k=hd][n=key]
    }

    // V B-frags straight from vT strip: B[k=key32][n=hd] = vT[c][32u + q*8 ..+7]
    short8 vBf[(TTP+1)/2];
    #pragma unroll
    for (int u = 0; u < (TTP+1)/2; ++u) if (u < ((T+1)>>1))
      vBf[u] = *(const short8*)&Pb[c*PSTR + 32*u + q*8];

    // ---- per query tile: S^T scores, per-lane softmax, PV (no barriers)
    #pragma unroll
    for (int t = 0; t < TTP; ++t) if (t < T){
      f32x4 St[TTP];
      #pragma unroll
      for (int tk = 0; tk < TTP; ++tk) if (tk < T){
        St[tk] = MFMA_B16(kBf[tk], qAf[t], Z4);     // C [key][query] = S^T
        #pragma unroll
        for (int r = 0; r < 4; ++r){
          const int key = 16*tk + 4*q + r;
          if (key >= Lv) St[tk][r] = -1e30f;        // mask padded keys
        }
      }
      // softmax for query = c (per-lane): keys live in 4 regs x T tiles x 4 q-groups
      f32x4 mm = {-1e30f,-1e30f,-1e30f,-1e30f};
      #pragma unroll
      for (int tk = 0; tk < TTP; ++tk) if (tk < T){
        mm[0]=fmaxf(mm[0],St[tk][0]); mm[1]=fmaxf(mm[1],St[tk][1]);
        mm[2]=fmaxf(mm[2],St[tk][2]); mm[3]=fmaxf(mm[3],St[tk][3]);
      }
      float m = fmaxf(fmaxf(mm[0],mm[1]), fmaxf(mm[2],mm[3]));
      m = fmaxf(m, __shfl_xor(m, 16));
      m = fmaxf(m, __shfl_xor(m, 32));
      f32x4 ss = Z4;
      #pragma unroll
      for (int tk = 0; tk < TTP; ++tk) if (tk < T){
        #pragma unroll
        for (int r = 0; r < 4; ++r){
          float e = __expf(St[tk][r] - m);
          St[tk][r] = e; ss[r] += e;
        }
      }
      float sum = (ss[0]+ss[1]) + (ss[2]+ss[3]);
      sum += __shfl_xor(sum, 16);
      sum += __shfl_xor(sum, 32);
      const float inv = 1.0f / sum;
      // write normalized P strip: row = query c, 4 consecutive keys per lane (b64)
      #pragma unroll
      for (int tk = 0; tk < TTP; ++tk) if (tk < T){
        short4v p4;
        #pragma unroll
        for (int r = 0; r < 4; ++r) p4[r] = (short)f2bf(St[tk][r] * inv);
        *(short4v*)&Pb[c*PSTR + 16*tk + 4*q] = p4;
      }
      f32x4 o = Z4;
      #pragma unroll
      for (int u = 0; u < (TTP+1)/2; ++u) if (u < ((T+1)>>1)){
        const short8 ap = *(const short8*)&Pb[c*PSTR + 32*u + q*8];  // A[m=query][k=key]
        o = MFMA_B16(ap, vBf[u], o);                                 // C [query][hd]
      }
      short4v ob;
      #pragma unroll
      for (int r = 0; r < 4; ++r) ob[r] = (short)f2bf(o[r]);
      of[hh][t] = ob;
    }
  } // hh

  __syncthreads();   // all waves done reading sF/sQK
  #pragma unroll
  for (int hh = 0; hh < 2; ++hh){
    const int h = wv*2 + hh;
    #pragma unroll
    for (int t = 0; t < TTP; ++t) if (t < T){
      #pragma unroll
      for (int r = 0; r < 4; ++r)
        sF[(16*t + 4*q + r)*STR + h*16 + c] = (unsigned short)of[hh][t][r];
    }
  }
  __syncthreads();   // O complete

  // ---- out projection: wave handles query tiles {wv, wv+4}
  float bo_r[8];
  #pragma unroll
  for (int ct = 0; ct < 8; ++ct) bo_r[ct] = opb[ct*16 + c];
  #pragma unroll
  for (int ti = 0; ti < 2; ++ti){
    const int t = wv + ti*4;
    if (t < T){
      f32x4 acc[8];
      #pragma unroll
      for (int ct = 0; ct < 8; ++ct) acc[ct] = Z4;
      #pragma unroll
      for (int p = 0; p < 4; ++p){
        const short8 ao = *(const short8*)&sF[(16*t + c)*STR + p*32 + q*8];
        #pragma unroll
        for (int ct = 0; ct < 8; ++ct){
          const short8 bw = *(const short8*)&wout[(ct*16 + c)*128 + p*32 + q*8];
          acc[ct] = MFMA_B16(ao, bw, acc[ct]);
        }
      }
      #pragma unroll
      for (int r = 0; r < 4; ++r){
        const int l = 16*t + 4*q + r;
        if (l < Lv){
          const int tok = inds[ibase + l];
          float* orow = out + (long)tok*128;
          #pragma unroll
          for (int ct = 0; ct < 8; ++ct)
            orow[ct*16 + c] = acc[ct][r] + bo_r[ct];
        }
      }
    }
  }
}

extern "C" void kernel_launch(void* const* d_in, const int* in_sizes, int n_in,
                              void* d_out, int out_size, void* d_ws, size_t ws_size,
                              hipStream_t stream) {
  const float* feat = (const float*)d_in[0];
  const float* pos1 = (const float*)d_in[1];
  const float* pos2 = (const float*)d_in[2];
  const float* ipw  = (const float*)d_in[3];
  const float* ipb  = (const float*)d_in[4];
  const float* opw  = (const float*)d_in[5];
  const float* opb  = (const float*)d_in[6];
  const int*   inds1 = (const int*)d_in[7];
  const int*   inds2 = (const int*)d_in[8];
  float* out = (float*)d_out;
  unsigned short* wbf = (unsigned short*)d_ws;   // 384*128 + 128*128 bf16
  unsigned short* wob = wbf + 384*128;

  prep_w<<<dim3(256), dim3(256), 0, stream>>>(ipw, opw, wbf);

  // group2 (L=100): TTP=7. LDS = (2*112*136 + 4*16*136 + 4*16*24)*2 = 81408 B
  // -> exactly 2 blocks/CU (163840/81408).
  {
    const int lds2 = (2*112*STR + 4*16*(16*8 + 8) + 4*16*24) * 2;
    hipFuncSetAttribute((const void*)fused_attn<7>,
                        hipFuncAttributeMaxDynamicSharedMemorySize, lds2);
    fused_attn<7><<<dim3(1024), dim3(256), lds2, stream>>>(
        feat, pos2, inds2, 100, wbf, wob, ipb, opb, out);
  }
  // group1 (L=36): TTP=3. LDS = (2*48*136 + 4*16*72 + 4*16*24)*2 = 38400 B
  // -> 4 blocks/CU.
  {
    const int lds1 = (2*48*STR + 4*16*(16*4 + 8) + 4*16*24) * 2;
    hipFuncSetAttribute((const void*)fused_attn<3>,
                        hipFuncAttributeMaxDynamicSharedMemorySize, lds1);
    fused_attn<3><<<dim3(4096), dim3(256), lds1, stream>>>(
        feat, pos1, inds1, 36, wbf, wob, ipb, opb, out);
  }
}

// Round 8
// 457.563 us; speedup vs baseline: 1.0981x; 1.0384x over previous
//
#include <hip/hip_runtime.h>

typedef __attribute__((ext_vector_type(4))) float f32x4;
typedef __attribute__((ext_vector_type(8))) short short8;
typedef __attribute__((ext_vector_type(4))) short short4v;

#define MFMA_B16(a,b,c) __builtin_amdgcn_mfma_f32_16x16x32_bf16((a),(b),(c),0,0,0)

static __device__ __forceinline__ unsigned short f2bf(float x){
  unsigned int u = __float_as_uint(x);
  u += 0x7fffu + ((u >> 16) & 1u);
  return (unsigned short)(u >> 16);
}

static __device__ __forceinline__ short8 pack8(f32x4 a, f32x4 b){
  short8 r;
  r[0]=(short)f2bf(a[0]); r[1]=(short)f2bf(a[1]); r[2]=(short)f2bf(a[2]); r[3]=(short)f2bf(a[3]);
  r[4]=(short)f2bf(b[0]); r[5]=(short)f2bf(b[1]); r[6]=(short)f2bf(b[2]); r[7]=(short)f2bf(b[3]);
  return r;
}

static __device__ __forceinline__ short4v pack4(const f32x4& a){
  short4v r;
  r[0]=(short)f2bf(a[0]); r[1]=(short)f2bf(a[1]); r[2]=(short)f2bf(a[2]); r[3]=(short)f2bf(a[3]);
  return r;
}

__global__ void prep_w(const float* __restrict__ ipw, const float* __restrict__ opw,
                       unsigned short* __restrict__ wbf){
  int i = blockIdx.x * 256 + threadIdx.x;
  float v = (i < 384*128) ? ipw[i] : opw[i - 384*128];
  wbf[i] = f2bf(v);
}

#define STR 136   // shorts per staged row (128 + 8 pad)

// ============================ group2 kernel ============================
// (unchanged from R7: 256 threads, 2 heads/wave, TTP=7, LDS-roundtrip xpose)
template<int TTP>
__global__ __launch_bounds__(256, 2)
void fused_attn(const float* __restrict__ feat,
                const float* __restrict__ pos,
                const int* __restrict__ inds,
                int LW,
                const unsigned short* __restrict__ wqkv,   // bf16 [384][128]
                const unsigned short* __restrict__ wout,   // bf16 [128][128]
                const float* __restrict__ ipb, const float* __restrict__ opb,
                float* __restrict__ out)
{
  constexpr int PSTR = 16*(TTP+1) + 8;   // P/vT strip row length
  constexpr int STRT = 24;               // transient transpose strip row length
  extern __shared__ __align__(16) unsigned short smem[];
  unsigned short* sQK = smem;                     // [16*TTP][STR] bf16 (f+pos)
  unsigned short* sF  = smem + 16*TTP*STR;        // [16*TTP][STR] bf16 f, reused for O
  unsigned short* sPb = smem + 2*16*TTP*STR;      // per-wave [16][PSTR] vT/P strips
  unsigned short* sTs = smem + 2*16*TTP*STR + 4*16*PSTR;  // per-wave [16][STRT]

  const int w = blockIdx.x;
  const int Lv = (w & 1) ? (LW >> 1) : LW;
  const int T  = (Lv + 15) >> 4;              // query/key tiles (<= TTP)
  const long ibase = (long)w * LW;
  const int tid = threadIdx.x;
  const int wv = tid >> 6, lane = tid & 63, c = lane & 15, q = lane >> 4;
  const short8 Z8 = {0,0,0,0,0,0,0,0};
  const f32x4  Z4 = {0.f,0.f,0.f,0.f};

  {
    const int rg = tid >> 4, ch = tid & 15;
    #pragma unroll
    for (int s = 0; s < TTP; ++s){
      if (s < T){
        const int row = s*16 + rg;
        short8 fv = Z8, qv = Z8;
        if (row < Lv){
          const int tok = inds[ibase + row];
          const float* fr = feat + (long)tok*128 + ch*8;
          const float* pr = pos + (ibase + row)*128 + ch*8;
          f32x4 f0 = *(const f32x4*)fr, f1 = *(const f32x4*)(fr+4);
          f32x4 p0 = *(const f32x4*)pr, p1 = *(const f32x4*)(pr+4);
          fv = pack8(f0, f1); qv = pack8(f0+p0, f1+p1);
        }
        *(short8*)&sF [row*STR + ch*8] = fv;
        *(short8*)&sQK[row*STR + ch*8] = qv;
      }
    }
  }
  __syncthreads();

  unsigned short* Pb = sPb + wv*16*PSTR;
  unsigned short* Ts = sTs + wv*16*STRT;
  if (T & 1){
    const short4v z4 = {0,0,0,0};
    *(short4v*)&Pb[c*PSTR + 16*T + 4*q] = z4;
  }
  short4v of[2][TTP];

  #pragma unroll
  for (int hh = 0; hh < 2; ++hh){
    const int h = wv*2 + hh;
    short8 bQ[4], bK[4], bV[4];
    const unsigned short* wr = wqkv + (h*16 + c)*128 + q*8;
    #pragma unroll
    for (int kk = 0; kk < 4; ++kk){
      bQ[kk] = *(const short8*)(wr + kk*32);
      bK[kk] = *(const short8*)(wr + kk*32 + 128*128);
      bV[kk] = *(const short8*)(wr + kk*32 + 2*128*128);
    }
    float bq_r[4], bk_r[4];
    #pragma unroll
    for (int r = 0; r < 4; ++r){
      bq_r[r] = ipb[h*16 + 4*q + r];
      bk_r[r] = ipb[128 + h*16 + 4*q + r];
    }
    const float bv_c = ipb[256 + h*16 + c];

    short8 qAf[TTP], kBf[TTP];

    #pragma unroll
    for (int t = 0; t < TTP; ++t) if (t < T){
      f32x4 qt = Z4, kt = Z4, vt = Z4;
      #pragma unroll
      for (int kk = 0; kk < 4; ++kk){
        const short8 aQ = *(const short8*)&sQK[(16*t + c)*STR + kk*32 + q*8];
        const short8 aF = *(const short8*)&sF [(16*t + c)*STR + kk*32 + q*8];
        qt = MFMA_B16(bQ[kk], aQ, qt);
        kt = MFMA_B16(bK[kk], aQ, kt);
        vt = MFMA_B16(aF, bV[kk], vt);
      }
      #pragma unroll
      for (int r = 0; r < 4; ++r){
        qt[r] = (qt[r] + bq_r[r]) * 0.25f;
        kt[r] += bk_r[r];
        const int key = 16*t + 4*q + r;
        vt[r] = (key < Lv) ? (vt[r] + bv_c) : 0.f;
      }
      *(short4v*)&Pb[c*PSTR + 16*t + 4*q] = pack4(vt);
      *(short4v*)&Ts[c*STRT + 4*q] = pack4(qt);
      const short8 qf = *(const short8*)&Ts[c*STRT + q*8];
      qAf[t] = (q < 2) ? qf : Z8;
      *(short4v*)&Ts[c*STRT + 4*q] = pack4(kt);
      const short8 kf = *(const short8*)&Ts[c*STRT + q*8];
      kBf[t] = (q < 2) ? kf : Z8;
    }

    short8 vBf[(TTP+1)/2];
    #pragma unroll
    for (int u = 0; u < (TTP+1)/2; ++u) if (u < ((T+1)>>1))
      vBf[u] = *(const short8*)&Pb[c*PSTR + 32*u + q*8];

    #pragma unroll
    for (int t = 0; t < TTP; ++t) if (t < T){
      f32x4 St[TTP];
      #pragma unroll
      for (int tk = 0; tk < TTP; ++tk) if (tk < T){
        St[tk] = MFMA_B16(kBf[tk], qAf[t], Z4);     // C [key][query] = S^T
        #pragma unroll
        for (int r = 0; r < 4; ++r){
          const int key = 16*tk + 4*q + r;
          if (key >= Lv) St[tk][r] = -1e30f;
        }
      }
      f32x4 mm = {-1e30f,-1e30f,-1e30f,-1e30f};
      #pragma unroll
      for (int tk = 0; tk < TTP; ++tk) if (tk < T){
        mm[0]=fmaxf(mm[0],St[tk][0]); mm[1]=fmaxf(mm[1],St[tk][1]);
        mm[2]=fmaxf(mm[2],St[tk][2]); mm[3]=fmaxf(mm[3],St[tk][3]);
      }
      float m = fmaxf(fmaxf(mm[0],mm[1]), fmaxf(mm[2],mm[3]));
      m = fmaxf(m, __shfl_xor(m, 16));
      m = fmaxf(m, __shfl_xor(m, 32));
      f32x4 ss = Z4;
      #pragma unroll
      for (int tk = 0; tk < TTP; ++tk) if (tk < T){
        #pragma unroll
        for (int r = 0; r < 4; ++r){
          float e = __expf(St[tk][r] - m);
          St[tk][r] = e; ss[r] += e;
        }
      }
      float sum = (ss[0]+ss[1]) + (ss[2]+ss[3]);
      sum += __shfl_xor(sum, 16);
      sum += __shfl_xor(sum, 32);
      const float inv = 1.0f / sum;
      #pragma unroll
      for (int tk = 0; tk < TTP; ++tk) if (tk < T){
        short4v p4;
        #pragma unroll
        for (int r = 0; r < 4; ++r) p4[r] = (short)f2bf(St[tk][r] * inv);
        *(short4v*)&Pb[c*PSTR + 16*tk + 4*q] = p4;
      }
      f32x4 o = Z4;
      #pragma unroll
      for (int u = 0; u < (TTP+1)/2; ++u) if (u < ((T+1)>>1)){
        const short8 ap = *(const short8*)&Pb[c*PSTR + 32*u + q*8];
        o = MFMA_B16(ap, vBf[u], o);
      }
      short4v ob;
      #pragma unroll
      for (int r = 0; r < 4; ++r) ob[r] = (short)f2bf(o[r]);
      of[hh][t] = ob;
    }
  } // hh

  __syncthreads();
  #pragma unroll
  for (int hh = 0; hh < 2; ++hh){
    const int h = wv*2 + hh;
    #pragma unroll
    for (int t = 0; t < TTP; ++t) if (t < T){
      #pragma unroll
      for (int r = 0; r < 4; ++r)
        sF[(16*t + 4*q + r)*STR + h*16 + c] = (unsigned short)of[hh][t][r];
    }
  }
  __syncthreads();

  float bo_r[8];
  #pragma unroll
  for (int ct = 0; ct < 8; ++ct) bo_r[ct] = opb[ct*16 + c];
  #pragma unroll
  for (int ti = 0; ti < 2; ++ti){
    const int t = wv + ti*4;
    if (t < T){
      f32x4 acc[8];
      #pragma unroll
      for (int ct = 0; ct < 8; ++ct) acc[ct] = Z4;
      #pragma unroll
      for (int p = 0; p < 4; ++p){
        const short8 ao = *(const short8*)&sF[(16*t + c)*STR + p*32 + q*8];
        #pragma unroll
        for (int ct = 0; ct < 8; ++ct){
          const short8 bw = *(const short8*)&wout[(ct*16 + c)*128 + p*32 + q*8];
          acc[ct] = MFMA_B16(ao, bw, acc[ct]);
        }
      }
      #pragma unroll
      for (int r = 0; r < 4; ++r){
        const int l = 16*t + 4*q + r;
        if (l < Lv){
          const int tok = inds[ibase + l];
          float* orow = out + (long)tok*128;
          #pragma unroll
          for (int ct = 0; ct < 8; ++ct)
            orow[ct*16 + c] = acc[ct][r] + bo_r[ct];
        }
      }
    }
  }
}

// ============================ group1 kernel ============================
// 512 threads = 8 waves covering TWO windows per block: waves 0-3 -> window
// 2b (even, T=3), waves 4-7 -> window 2b+1 (odd, T=2). Each wave keeps the
// PROVEN R5/R7 2-head structure (76 VGPR < 128), so __launch_bounds__(512,4)
// is spill-free and 2 blocks/CU = 16 waves/CU (double R7's g1 occupancy).
#define TT3 3
#define PSTR3 (16*(TT3+1) + 8)   // 72
#define STRT3 24
#define HALF3 (2*48*STR + 4*16*PSTR3 + 4*16*STRT3)   // shorts per window half

__global__ __launch_bounds__(512, 4)
void fused_attn3_2w(const float* __restrict__ feat,
                    const float* __restrict__ pos,
                    const int* __restrict__ inds,
                    const unsigned short* __restrict__ wqkv,
                    const unsigned short* __restrict__ wout,
                    const float* __restrict__ ipb, const float* __restrict__ opb,
                    float* __restrict__ out)
{
  extern __shared__ __align__(16) unsigned short smem[];
  const int tid = threadIdx.x;
  const int wv8 = tid >> 6;                  // 0..7
  const int wh  = wv8 >> 2;                  // window half 0/1
  const int wv  = wv8 & 3;                   // wave within half
  const int lane = tid & 63, c = lane & 15, q = lane >> 4;

  unsigned short* base = smem + wh*HALF3;
  unsigned short* sQK = base;                     // [48][STR]
  unsigned short* sF  = base + 48*STR;            // [48][STR], O later
  unsigned short* sPb = base + 2*48*STR;          // 4 x [16][PSTR3]
  unsigned short* sTs = sPb + 4*16*PSTR3;         // 4 x [16][STRT3]

  const int w = blockIdx.x*2 + wh;
  const int LW = 36;
  const int Lv = wh ? 18 : 36;               // w parity == wh
  const int T  = wh ? 2 : 3;
  const long ibase = (long)w * LW;
  const short8 Z8 = {0,0,0,0,0,0,0,0};
  const f32x4  Z4 = {0.f,0.f,0.f,0.f};

  // ---- stage f and qk=f+pos: each half's 256 threads stage its window
  {
    const int ltid = tid & 255;
    const int rg = ltid >> 4, ch = ltid & 15;
    #pragma unroll
    for (int s = 0; s < TT3; ++s){
      if (s < T){
        const int row = s*16 + rg;
        short8 fv = Z8, qv = Z8;
        if (row < Lv){
          const int tok = inds[ibase + row];
          const float* fr = feat + (long)tok*128 + ch*8;
          const float* pr = pos + (ibase + row)*128 + ch*8;
          f32x4 f0 = *(const f32x4*)fr, f1 = *(const f32x4*)(fr+4);
          f32x4 p0 = *(const f32x4*)pr, p1 = *(const f32x4*)(pr+4);
          fv = pack8(f0, f1); qv = pack8(f0+p0, f1+p1);
        }
        *(short8*)&sF [row*STR + ch*8] = fv;
        *(short8*)&sQK[row*STR + ch*8] = qv;
      }
    }
  }
  __syncthreads();

  unsigned short* Pb = sPb + wv*16*PSTR3;
  unsigned short* Ts = sTs + wv*16*STRT3;
  if (T & 1){
    const short4v z4 = {0,0,0,0};
    *(short4v*)&Pb[c*PSTR3 + 16*T + 4*q] = z4;
  }
  short4v of[2][TT3];

  #pragma unroll
  for (int hh = 0; hh < 2; ++hh){
    const int h = wv*2 + hh;
    short8 bQ[4], bK[4], bV[4];
    const unsigned short* wr = wqkv + (h*16 + c)*128 + q*8;
    #pragma unroll
    for (int kk = 0; kk < 4; ++kk){
      bQ[kk] = *(const short8*)(wr + kk*32);
      bK[kk] = *(const short8*)(wr + kk*32 + 128*128);
      bV[kk] = *(const short8*)(wr + kk*32 + 2*128*128);
    }
    float bq_r[4], bk_r[4];
    #pragma unroll
    for (int r = 0; r < 4; ++r){
      bq_r[r] = ipb[h*16 + 4*q + r];
      bk_r[r] = ipb[128 + h*16 + 4*q + r];
    }
    const float bv_c = ipb[256 + h*16 + c];

    short8 qAf[TT3], kBf[TT3];

    #pragma unroll
    for (int t = 0; t < TT3; ++t) if (t < T){
      f32x4 qt = Z4, kt = Z4, vt = Z4;
      #pragma unroll
      for (int kk = 0; kk < 4; ++kk){
        const short8 aQ = *(const short8*)&sQK[(16*t + c)*STR + kk*32 + q*8];
        const short8 aF = *(const short8*)&sF [(16*t + c)*STR + kk*32 + q*8];
        qt = MFMA_B16(bQ[kk], aQ, qt);
        kt = MFMA_B16(bK[kk], aQ, kt);
        vt = MFMA_B16(aF, bV[kk], vt);
      }
      #pragma unroll
      for (int r = 0; r < 4; ++r){
        qt[r] = (qt[r] + bq_r[r]) * 0.25f;
        kt[r] += bk_r[r];
        const int key = 16*t + 4*q + r;
        vt[r] = (key < Lv) ? (vt[r] + bv_c) : 0.f;
      }
      *(short4v*)&Pb[c*PSTR3 + 16*t + 4*q] = pack4(vt);
      *(short4v*)&Ts[c*STRT3 + 4*q] = pack4(qt);
      const short8 qf = *(const short8*)&Ts[c*STRT3 + q*8];
      qAf[t] = (q < 2) ? qf : Z8;
      *(short4v*)&Ts[c*STRT3 + 4*q] = pack4(kt);
      const short8 kf = *(const short8*)&Ts[c*STRT3 + q*8];
      kBf[t] = (q < 2) ? kf : Z8;
    }

    short8 vBf[2];
    #pragma unroll
    for (int u = 0; u < 2; ++u) if (u < ((T+1)>>1))
      vBf[u] = *(const short8*)&Pb[c*PSTR3 + 32*u + q*8];

    #pragma unroll
    for (int t = 0; t < TT3; ++t) if (t < T){
      f32x4 St[TT3];
      #pragma unroll
      for (int tk = 0; tk < TT3; ++tk) if (tk < T){
        St[tk] = MFMA_B16(kBf[tk], qAf[t], Z4);     // C [key][query] = S^T
        #pragma unroll
        for (int r = 0; r < 4; ++r){
          const int key = 16*tk + 4*q + r;
          if (key >= Lv) St[tk][r] = -1e30f;
        }
      }
      f32x4 mm = {-1e30f,-1e30f,-1e30f,-1e30f};
      #pragma unroll
      for (int tk = 0; tk < TT3; ++tk) if (tk < T){
        mm[0]=fmaxf(mm[0],St[tk][0]); mm[1]=fmaxf(mm[1],St[tk][1]);
        mm[2]=fmaxf(mm[2],St[tk][2]); mm[3]=fmaxf(mm[3],St[tk][3]);
      }
      float m = fmaxf(fmaxf(mm[0],mm[1]), fmaxf(mm[2],mm[3]));
      m = fmaxf(m, __shfl_xor(m, 16));
      m = fmaxf(m, __shfl_xor(m, 32));
      f32x4 ss = Z4;
      #pragma unroll
      for (int tk = 0; tk < TT3; ++tk) if (tk < T){
        #pragma unroll
        for (int r = 0; r < 4; ++r){
          float e = __expf(St[tk][r] - m);
          St[tk][r] = e; ss[r] += e;
        }
      }
      float sum = (ss[0]+ss[1]) + (ss[2]+ss[3]);
      sum += __shfl_xor(sum, 16);
      sum += __shfl_xor(sum, 32);
      const float inv = 1.0f / sum;
      #pragma unroll
      for (int tk = 0; tk < TT3; ++tk) if (tk < T){
        short4v p4;
        #pragma unroll
        for (int r = 0; r < 4; ++r) p4[r] = (short)f2bf(St[tk][r] * inv);
        *(short4v*)&Pb[c*PSTR3 + 16*tk + 4*q] = p4;
      }
      f32x4 o = Z4;
      #pragma unroll
      for (int u = 0; u < 2; ++u) if (u < ((T+1)>>1)){
        const short8 ap = *(const short8*)&Pb[c*PSTR3 + 32*u + q*8];
        o = MFMA_B16(ap, vBf[u], o);
      }
      short4v ob;
      #pragma unroll
      for (int r = 0; r < 4; ++r) ob[r] = (short)f2bf(o[r]);
      of[hh][t] = ob;
    }
  } // hh

  __syncthreads();   // all waves done reading sQK/sF (both halves)
  #pragma unroll
  for (int hh = 0; hh < 2; ++hh){
    const int h = wv*2 + hh;
    #pragma unroll
    for (int t = 0; t < TT3; ++t) if (t < T){
      #pragma unroll
      for (int r = 0; r < 4; ++r)
        sF[(16*t + 4*q + r)*STR + h*16 + c] = (unsigned short)of[hh][t][r];
    }
  }
  __syncthreads();   // O complete

  // ---- out projection: wave handles query tile wv of its window
  {
    const int t = wv;
    if (t < T){
      float bo_r[8];
      #pragma unroll
      for (int ct = 0; ct < 8; ++ct) bo_r[ct] = opb[ct*16 + c];
      f32x4 acc[8];
      #pragma unroll
      for (int ct = 0; ct < 8; ++ct) acc[ct] = Z4;
      #pragma unroll
      for (int p = 0; p < 4; ++p){
        const short8 ao = *(const short8*)&sF[(16*t + c)*STR + p*32 + q*8];
        #pragma unroll
        for (int ct = 0; ct < 8; ++ct){
          const short8 bw = *(const short8*)&wout[(ct*16 + c)*128 + p*32 + q*8];
          acc[ct] = MFMA_B16(ao, bw, acc[ct]);
        }
      }
      #pragma unroll
      for (int r = 0; r < 4; ++r){
        const int l = 16*t + 4*q + r;
        if (l < Lv){
          const int tok = inds[ibase + l];
          float* orow = out + (long)tok*128;
          #pragma unroll
          for (int ct = 0; ct < 8; ++ct)
            orow[ct*16 + c] = acc[ct][r] + bo_r[ct];
        }
      }
    }
  }
}

extern "C" void kernel_launch(void* const* d_in, const int* in_sizes, int n_in,
                              void* d_out, int out_size, void* d_ws, size_t ws_size,
                              hipStream_t stream) {
  const float* feat = (const float*)d_in[0];
  const float* pos1 = (const float*)d_in[1];
  const float* pos2 = (const float*)d_in[2];
  const float* ipw  = (const float*)d_in[3];
  const float* ipb  = (const float*)d_in[4];
  const float* opw  = (const float*)d_in[5];
  const float* opb  = (const float*)d_in[6];
  const int*   inds1 = (const int*)d_in[7];
  const int*   inds2 = (const int*)d_in[8];
  float* out = (float*)d_out;
  unsigned short* wbf = (unsigned short*)d_ws;   // 384*128 + 128*128 bf16
  unsigned short* wob = wbf + 384*128;

  prep_w<<<dim3(256), dim3(256), 0, stream>>>(ipw, opw, wbf);

  // group2 (L=100): TTP=7, 256 threads. LDS = 81408 B -> 2 blocks/CU.
  {
    const int lds2 = (2*112*STR + 4*16*(16*8 + 8) + 4*16*24) * 2;
    hipFuncSetAttribute((const void*)fused_attn<7>,
                        hipFuncAttributeMaxDynamicSharedMemorySize, lds2);
    fused_attn<7><<<dim3(1024), dim3(256), lds2, stream>>>(
        feat, pos2, inds2, 100, wbf, wob, ipb, opb, out);
  }
  // group1 (L=36): 512 threads, 2 windows/block, 2048 blocks.
  // LDS = 2*HALF3*2 = 76800 B -> 2 blocks/CU = 16 waves/CU.
  {
    const int lds1 = 2*HALF3*2;
    hipFuncSetAttribute((const void*)fused_attn3_2w,
                        hipFuncAttributeMaxDynamicSharedMemorySize, lds1);
    fused_attn3_2w<<<dim3(2048), dim3(512), lds1, stream>>>(
        feat, pos1, inds1, wbf, wob, ipb, opb, out);
  }
}